// Round 5
// baseline (1123.789 us; speedup 1.0000x reference)
//
#include <hip/hip_runtime.h>

#define NN 100000   // nodes
#define NE 500000   // edges per relation
#define NR 4        // relations
#define NL 4        // layers
#define FIN 64      // input features
#define D 128       // embedding dim
#define NGR 64      // graphs

#define SCH 1024
#define SBLK ((NN + SCH - 1) / SCH)   // 98

typedef __attribute__((ext_vector_type(8))) short short8;
typedef __attribute__((ext_vector_type(4))) float f32x4;
typedef __attribute__((ext_vector_type(2))) unsigned short u16x2;
typedef unsigned short ushort;
typedef unsigned int uint;

__device__ __forceinline__ ushort f2b(float f) {
    uint u = __float_as_uint(f);
    uint r = (u + 0x7fffu + ((u >> 16) & 1u)) >> 16;  // RNE
    return (ushort)r;
}
__device__ __forceinline__ float b2f(ushort b) {
    return __uint_as_float(((uint)b) << 16);
}
// monotone bf16 -> u16 key (order-isomorphic, exact bijection)
__device__ __forceinline__ ushort enc16(ushort u) {
    return u ^ (ushort)((((short)u) >> 15) | (short)0x8000);
}
__device__ __forceinline__ ushort dec16(ushort k) {
    return k ^ (ushort)((((short)(k ^ 0x8000)) >> 15) | (short)0x8000);
}
__device__ __forceinline__ u16x2 vmax2(u16x2 a, u16x2 b) {
#if __has_builtin(__builtin_elementwise_max)
    return __builtin_elementwise_max(a, b);
#else
    u16x2 r;
    r.x = a.x > b.x ? a.x : b.x;
    r.y = a.y > b.y ? a.y : b.y;
    return r;
#endif
}

// ---------------- utility ----------------
__global__ void zero_i32(int* __restrict__ p, int n) {
    int i = blockIdx.x * blockDim.x + threadIdx.x;
    if (i < n) p[i] = 0;
}
__global__ void zero_f32(float* __restrict__ p, int n) {
    int i = blockIdx.x * blockDim.x + threadIdx.x;
    if (i < n) p[i] = 0.f;
}
__global__ void xcvt(const float* __restrict__ x, ushort* __restrict__ xb, int n) {
    int i = blockIdx.x * blockDim.x + threadIdx.x;
    if (i < n) xb[i] = f2b(x[i]);
}

// W fp32 [nmat][K x 128] -> bf16 MFMA B-fragment order
__global__ void wperm_kernel(const float* __restrict__ W, ushort* __restrict__ dst,
                             int K, int total) {
    int i = blockIdx.x * blockDim.x + threadIdx.x;
    if (i >= total) return;
    int per = K * 128;
    int mi = i / per;
    int o = i - mi * per;
    int j = o & 7, lane = (o >> 3) & 63, rest = o >> 9;
    int K032 = K / 32;
    int k0 = rest % K032, t = rest / K032;
    int k = k0 * 32 + (lane >> 4) * 8 + j;
    int n = t * 16 + (lane & 15);
    dst[i] = f2b(W[(size_t)mi * per + k * 128 + n]);
}

// ---------------- CSR build (all relations in one dispatch) ----------------
__global__ void count_all(const int* __restrict__ e0, const int* __restrict__ e1,
                          const int* __restrict__ e2, const int* __restrict__ e3,
                          int* __restrict__ cnt) {
    int i = blockIdx.x * blockDim.x + threadIdx.x;
    if (i >= NR * NE) return;
    int r = i / NE, j = i - r * NE;
    const int* ei = (r == 0) ? e0 : (r == 1) ? e1 : (r == 2) ? e2 : e3;
    atomicAdd(&cnt[r * NN + ei[NE + j]], 1);
}

__global__ __launch_bounds__(256) void scan1(const int* __restrict__ counts,
                                             int* __restrict__ partial) {
    int r = blockIdx.x / SBLK, b = blockIdx.x % SBLK;
    const int* cnt = counts + (size_t)r * NN + (size_t)b * SCH;
    int n = NN - b * SCH; if (n > SCH) n = SCH;
    int t = threadIdx.x;
    int s = 0;
    for (int i = t; i < n; i += 256) s += cnt[i];
    __shared__ int sd[256];
    sd[t] = s; __syncthreads();
    for (int d = 128; d; d >>= 1) { if (t < d) sd[t] += sd[t + d]; __syncthreads(); }
    if (t == 0) partial[r * SBLK + b] = sd[0];
}

__global__ __launch_bounds__(128) void scan2(int* __restrict__ partial, int* __restrict__ offs) {
    int r = blockIdx.x;
    int* p = partial + r * SBLK;
    int t = threadIdx.x;
    __shared__ int sd[128];
    int v = (t < SBLK) ? p[t] : 0;
    sd[t] = v; __syncthreads();
    for (int d = 1; d < 128; d <<= 1) {
        int u = (t >= d) ? sd[t - d] : 0;
        __syncthreads();
        sd[t] += u;
        __syncthreads();
    }
    if (t < SBLK) p[t] = sd[t] - v;
    if (t == 0) offs[(size_t)r * (NN + 1) + NN] = NE;
}

__global__ __launch_bounds__(256) void scan3(int* __restrict__ counts,
                                             const int* __restrict__ partial,
                                             int* __restrict__ offs) {
    int r = blockIdx.x / SBLK, b = blockIdx.x % SBLK;
    int t = threadIdx.x;
    int* cnt = counts + (size_t)r * NN;
    int* off = offs + (size_t)r * (NN + 1);
    int i0 = b * SCH + t * 4;
    int c[4];
#pragma unroll
    for (int j = 0; j < 4; j++) c[j] = (i0 + j < NN) ? cnt[i0 + j] : 0;
    int ts = c[0] + c[1] + c[2] + c[3];
    __shared__ int sd[256];
    sd[t] = ts; __syncthreads();
    for (int d = 1; d < 256; d <<= 1) {
        int u = (t >= d) ? sd[t - d] : 0;
        __syncthreads();
        sd[t] += u;
        __syncthreads();
    }
    int run = partial[r * SBLK + b] + sd[t] - ts;
#pragma unroll
    for (int j = 0; j < 4; j++) {
        if (i0 + j < NN) {
            off[i0 + j] = run;
            cnt[i0 + j] = run;
            run += c[j];
        }
    }
}

// stores BYTE offsets (src * D * 2) so agg needs no per-edge shift
__global__ void fill_all(const int* __restrict__ e0, const int* __restrict__ e1,
                         const int* __restrict__ e2, const int* __restrict__ e3,
                         int* __restrict__ cur, int* __restrict__ esrc) {
    int i = blockIdx.x * blockDim.x + threadIdx.x;
    if (i >= NR * NE) return;
    int r = i / NE, j = i - r * NE;
    const int* ei = (r == 0) ? e0 : (r == 1) ? e1 : (r == 2) ? e2 : e3;
    int pos = atomicAdd(&cur[r * NN + ei[NE + j]], 1);
    esrc[(size_t)r * NE + pos] = ei[j] * (D * 2);
}

// ---------------- bf16 MFMA GEMM ----------------
// MODE 0: store bf16(acc).  MODE 1: store monotone key16 (for scatter-max m).
template <int K, int MODE>
__global__ __launch_bounds__(256) void mgemm(const ushort* __restrict__ A,
                                             const ushort* __restrict__ Bp,
                                             const float* __restrict__ bias,
                                             ushort* __restrict__ Ch) {
    constexpr int K032 = K / 32;
    __shared__ ushort Bs[8 * K032 * 64 * 8];
    const int tid = threadIdx.x;
    for (int i = tid; i < K * 16; i += 256)
        ((float4*)Bs)[i] = ((const float4*)Bp)[i];
    const int lane = tid & 63, wave = tid >> 6;
    const int quad = lane >> 4, l15 = lane & 15;
    const int ch = wave & 1, rg = wave >> 1;
    __syncthreads();
    short8 breg[4][K032];
#pragma unroll
    for (int tt = 0; tt < 4; tt++)
#pragma unroll
        for (int k0 = 0; k0 < K032; k0++)
            breg[tt][k0] = *(const short8*)&Bs[(size_t)(((ch * 4 + tt) * K032 + k0) * 64 + lane) * 8];
    float bv[4] = {0.f, 0.f, 0.f, 0.f};
    if (bias)
#pragma unroll
        for (int tt = 0; tt < 4; tt++) bv[tt] = bias[(ch * 4 + tt) * 16 + l15];
    for (int tile = blockIdx.x; tile < NN / 32; tile += gridDim.x) {
        const int row0 = tile * 32 + rg * 16;
        const ushort* Ar = A + (size_t)(row0 + l15) * K + quad * 8;
        short8 a[K032];
#pragma unroll
        for (int k0 = 0; k0 < K032; k0++) a[k0] = *(const short8*)(Ar + k0 * 32);
        f32x4 acc[4];
#pragma unroll
        for (int tt = 0; tt < 4; tt++) acc[tt] = (f32x4){bv[tt], bv[tt], bv[tt], bv[tt]};
#pragma unroll
        for (int k0 = 0; k0 < K032; k0++)
#pragma unroll
            for (int tt = 0; tt < 4; tt++)
                acc[tt] = __builtin_amdgcn_mfma_f32_16x16x32_bf16(a[k0], breg[tt][k0], acc[tt], 0, 0, 0);
#pragma unroll
        for (int tt = 0; tt < 4; tt++) {
            const int col = (ch * 4 + tt) * 16 + l15;
#pragma unroll
            for (int r = 0; r < 4; r++) {
                ushort v = f2b(acc[tt][r]);
                if (MODE == 1) v = enc16(v);
                Ch[(size_t)(row0 + quad * 4 + r) * D + col] = v;
            }
        }
    }
}

// ---------------- fused multi-relation scatter-max over key16 messages ----------------
__global__ __launch_bounds__(256) void agg_kernel(const ushort* __restrict__ mb,
                                                  const int* __restrict__ offs,
                                                  const int* __restrict__ esrc,
                                                  int G,
                                                  const ushort* __restrict__ base,
                                                  ushort* __restrict__ outh,
                                                  int do_relu) {
    int wv = threadIdx.x >> 6;
    int lane = threadIdx.x & 63;
    int node = blockIdx.x * 4 + wv;
    if (node >= NN) return;
    uint bp = ((const uint*)(base + (size_t)node * D))[lane];
    float rx = __uint_as_float(bp << 16), ry = __uint_as_float(bp & 0xffff0000u);
    for (int g = 0; g < G; g++) {
        const int* off = offs + (size_t)g * (NN + 1);
        const char* ml = (const char*)(mb + (size_t)g * NN * D) + lane * 4;
        const int* es = esrc + (size_t)g * NE;
        int beg = off[node], end = off[node + 1];
        int nd = end - beg;
        if (nd <= 0) continue;
        u16x2 a0 = (u16x2)0, a1 = (u16x2)0, a2 = (u16x2)0, a3 = (u16x2)0;
        for (int c0 = 0; c0 < nd; c0 += 64) {
            int cnt = nd - c0; if (cnt > 64) cnt = 64;
            int s_l = (lane < cnt) ? es[beg + c0 + lane] : 0;
            int i = 0;
            for (; i + 4 <= cnt; i += 4) {
                int s0 = __shfl(s_l, i + 0);
                int s1 = __shfl(s_l, i + 1);
                int s2 = __shfl(s_l, i + 2);
                int s3 = __shfl(s_l, i + 3);
                u16x2 v0 = *(const u16x2*)(ml + s0);
                u16x2 v1 = *(const u16x2*)(ml + s1);
                u16x2 v2 = *(const u16x2*)(ml + s2);
                u16x2 v3 = *(const u16x2*)(ml + s3);
                a0 = vmax2(a0, v0);
                a1 = vmax2(a1, v1);
                a2 = vmax2(a2, v2);
                a3 = vmax2(a3, v3);
            }
            for (; i < cnt; i++) {
                int s = __shfl(s_l, i);
                a0 = vmax2(a0, *(const u16x2*)(ml + s));
            }
        }
        u16x2 am = vmax2(vmax2(a0, a1), vmax2(a2, a3));
        rx += b2f(dec16(am.x));
        ry += b2f(dec16(am.y));
    }
    if (do_relu) { rx = fmaxf(rx, 0.f); ry = fmaxf(ry, 0.f); }
    uint pk = (uint)f2b(rx) | ((uint)f2b(ry) << 16);
    ((uint*)(outh + (size_t)node * D))[lane] = pk;
}

// ---------------- global add pool (batch sorted), h in bf16 ----------------
#define PCH 256
__global__ __launch_bounds__(128) void pool_kernel(const ushort* __restrict__ h,
                                                   const int* __restrict__ batch,
                                                   float* __restrict__ out) {
    int c = threadIdx.x;
    int n0 = blockIdx.x * PCH;
    if (n0 >= NN) return;
    int n1 = n0 + PCH; if (n1 > NN) n1 = NN;
    int cur = batch[n0];
    float acc = 0.f;
    for (int n = n0; n < n1; n++) {
        int g = batch[n];
        if (g != cur) {
            atomicAdd(&out[cur * D + c], acc);
            acc = 0.f;
            cur = g;
        }
        acc += b2f(h[(size_t)n * D + c]);
    }
    atomicAdd(&out[cur * D + c], acc);
}

extern "C" void kernel_launch(void* const* d_in, const int* in_sizes, int n_in,
                              void* d_out, int out_size, void* d_ws, size_t ws_size,
                              hipStream_t stream) {
    const float* x = (const float*)d_in[0];
    const int* ei[4] = {(const int*)d_in[1], (const int*)d_in[2],
                        (const int*)d_in[3], (const int*)d_in[4]};
    const int* batch = (const int*)d_in[5];
    const float* emb_w = (const float*)d_in[6];
    const float* emb_b = (const float*)d_in[7];
    const float* root_w = (const float*)d_in[8];
    const float* root_b = (const float*)d_in[9];
    const float* conv_w = (const float*)d_in[10];
    float* out = (float*)d_out;

    const size_t WPT = (size_t)FIN * 128 + 20 * (size_t)128 * 128;  // permuted weights
    const size_t ints = (size_t)NR * (NN + 1) + (size_t)NR * NN + (size_t)NR * NE + NR * SBLK;
    int G = 1;
    for (int g = 4; g >= 2; g >>= 1) {
        size_t need = ((size_t)NN * D * (2 + g) + (size_t)NN * FIN + WPT) * 2 + ints * 4;
        if (ws_size >= need) { G = g; break; }
    }

    // workspace layout (all node buffers bf16/key16)
    ushort* hb = (ushort*)d_ws;                        // NN*D
    ushort* ob = hb + (size_t)NN * D;                  // NN*D (base)
    ushort* mbuf = ob + (size_t)NN * D;                // G*NN*D (key16)
    ushort* xb = mbuf + (size_t)G * NN * D;            // NN*FIN
    ushort* wp = xb + (size_t)NN * FIN;                // WPT
    int* offs = (int*)(wp + WPT);                      // NR*(NN+1)
    int* counts = offs + (size_t)NR * (NN + 1);        // NR*NN (-> cursor)
    int* esrc = counts + (size_t)NR * NN;              // NR*NE (byte offsets)
    int* partial = esrc + (size_t)NR * NE;             // NR*SBLK
    ushort* wpEmb = wp;
    ushort* wpRoot = wp + (size_t)FIN * 128;
    ushort* wpConv = wpRoot + (size_t)4 * 128 * 128;

    // ---- CSR build ----
    zero_i32<<<(NR * NN + 255) / 256, 256, 0, stream>>>(counts, NR * NN);
    count_all<<<(NR * NE + 255) / 256, 256, 0, stream>>>(ei[0], ei[1], ei[2], ei[3], counts);
    scan1<<<NR * SBLK, 256, 0, stream>>>(counts, partial);
    scan2<<<NR, 128, 0, stream>>>(partial, offs);
    scan3<<<NR * SBLK, 256, 0, stream>>>(counts, partial, offs);
    fill_all<<<(NR * NE + 255) / 256, 256, 0, stream>>>(ei[0], ei[1], ei[2], ei[3], counts, esrc);

    // ---- weight permute + input convert ----
    {
        int t1 = FIN * 128;
        wperm_kernel<<<(t1 + 255) / 256, 256, 0, stream>>>(emb_w, wpEmb, FIN, t1);
        int t2 = 4 * 128 * 128;
        wperm_kernel<<<(t2 + 255) / 256, 256, 0, stream>>>(root_w, wpRoot, 128, t2);
        int t3 = 16 * 128 * 128;
        wperm_kernel<<<(t3 + 255) / 256, 256, 0, stream>>>(conv_w, wpConv, 128, t3);
        int t4 = NN * FIN;
        xcvt<<<(t4 + 255) / 256, 256, 0, stream>>>(x, xb, t4);
    }

    // ---- embedding ----
    mgemm<FIN, 0><<<1024, 256, 0, stream>>>(xb, wpEmb, emb_b, hb);

    // ---- layers ----
    for (int l = 0; l < NL; l++) {
        mgemm<128, 0><<<1024, 256, 0, stream>>>(hb, wpRoot + (size_t)l * 128 * 128,
                                                root_b + (size_t)l * D, ob);
        for (int g0 = 0; g0 < NR; g0 += G) {
            for (int r = g0; r < g0 + G; r++)
                mgemm<128, 1><<<1024, 256, 0, stream>>>(
                    hb, wpConv + (size_t)(l * NR + r) * 128 * 128, nullptr,
                    mbuf + (size_t)(r - g0) * NN * D);
            int last = (g0 + G == NR);
            agg_kernel<<<(NN + 3) / 4, 256, 0, stream>>>(
                mbuf, offs + (size_t)g0 * (NN + 1), esrc + (size_t)g0 * NE, G,
                ob, last ? hb : ob, last ? 1 : 0);
        }
    }

    // ---- global add pool ----
    zero_f32<<<(NGR * D + 255) / 256, 256, 0, stream>>>(out, NGR * D);
    pool_kernel<<<(NN + PCH - 1) / PCH, 128, 0, stream>>>(hb, batch, out);
}

// Round 6
// 947.299 us; speedup vs baseline: 1.1863x; 1.1863x over previous
//
#include <hip/hip_runtime.h>

#define NN 100000   // nodes
#define NE 500000   // edges per relation
#define NR 4        // relations
#define NL 4        // layers
#define FIN 64      // input features
#define D 128       // embedding dim
#define NGR 64      // graphs

#define FP 8        // dst partitions (XCD round-robin heuristic)
#define PSZ ((NN + FP - 1) / FP)   // 12500 nodes per partition
#define EPB 4096    // edges per block chunk in slot_fill

typedef __attribute__((ext_vector_type(8))) short short8;
typedef __attribute__((ext_vector_type(4))) float f32x4;
typedef __attribute__((ext_vector_type(2))) unsigned short u16x2;
typedef unsigned short ushort;
typedef unsigned int uint;

__device__ __forceinline__ ushort f2b(float f) {
    uint u = __float_as_uint(f);
    uint r = (u + 0x7fffu + ((u >> 16) & 1u)) >> 16;  // RNE
    return (ushort)r;
}
__device__ __forceinline__ float b2f(ushort b) {
    return __uint_as_float(((uint)b) << 16);
}
// monotone bf16 -> u16 key (order-isomorphic, exact bijection)
__device__ __forceinline__ ushort enc16(ushort u) {
    return u ^ (ushort)((((short)u) >> 15) | (short)0x8000);
}
__device__ __forceinline__ ushort dec16(ushort k) {
    return k ^ (ushort)((((short)(k ^ 0x8000)) >> 15) | (short)0x8000);
}
__device__ __forceinline__ u16x2 vmax2(u16x2 a, u16x2 b) {
#if __has_builtin(__builtin_elementwise_max)
    return __builtin_elementwise_max(a, b);
#else
    u16x2 r;
    r.x = a.x > b.x ? a.x : b.x;
    r.y = a.y > b.y ? a.y : b.y;
    return r;
#endif
}

// ---------------- utility ----------------
__global__ void zero_i32(int* __restrict__ p, int n) {
    int i = blockIdx.x * blockDim.x + threadIdx.x;
    if (i < n) p[i] = 0;
}
__global__ void zero_f32(float* __restrict__ p, int n) {
    int i = blockIdx.x * blockDim.x + threadIdx.x;
    if (i < n) p[i] = 0.f;
}
__global__ void xcvt(const float* __restrict__ x, ushort* __restrict__ xb, int n) {
    int i = blockIdx.x * blockDim.x + threadIdx.x;
    if (i < n) xb[i] = f2b(x[i]);
}

// W fp32 [nmat][K x 128] -> bf16 MFMA B-fragment order
__global__ void wperm_kernel(const float* __restrict__ W, ushort* __restrict__ dst,
                             int K, int total) {
    int i = blockIdx.x * blockDim.x + threadIdx.x;
    if (i >= total) return;
    int per = K * 128;
    int mi = i / per;
    int o = i - mi * per;
    int j = o & 7, lane = (o >> 3) & 63, rest = o >> 9;
    int K032 = K / 32;
    int k0 = rest % K032, t = rest / K032;
    int k = k0 * 32 + (lane >> 4) * 8 + j;
    int n = t * 16 + (lane & 15);
    dst[i] = f2b(W[(size_t)mi * per + k * 128 + n]);
}

// ---------------- one-pass slotted adjacency build, XCD-partitioned ----------------
// slots[(r*NN + dst)*CAP + slot] = src byte-offset; deg[r*NN + dst] counts.
// Partition p (= blockIdx.x % FP, XCD round-robin) handles dst in [p*PSZ,(p+1)*PSZ):
// its dirty slot region (~CAP*PSZ*4*NR/FP bytes) stays L2-local -> no 16x write amp.
template <int CAP>
__global__ __launch_bounds__(256) void slot_fill(const int* __restrict__ e0,
                                                 const int* __restrict__ e1,
                                                 const int* __restrict__ e2,
                                                 const int* __restrict__ e3,
                                                 int* __restrict__ deg,
                                                 int* __restrict__ slots) {
    const int part = blockIdx.x % FP;
    const int chunk = blockIdx.x / FP;
    const int plo = part * PSZ;
    const int phi = (plo + PSZ < NN) ? plo + PSZ : NN;
    const int i0 = chunk * EPB;
    int i1 = i0 + EPB; if (i1 > NR * NE) i1 = NR * NE;
    for (int i = i0 + threadIdx.x; i < i1; i += 256) {
        int r = i / NE, j = i - r * NE;
        const int* ei = (r == 0) ? e0 : (r == 1) ? e1 : (r == 2) ? e2 : e3;
        int d = ei[NE + j];
        if (d >= plo && d < phi) {
            int s = ei[j];
            int slot = atomicAdd(&deg[r * NN + d], 1);
            if (slot < CAP)
                slots[((size_t)r * NN + d) * CAP + slot] = s * (D * 2);
        }
    }
}

// ---------------- bf16 MFMA GEMM (embedding / fallback) ----------------
template <int K, int MODE>
__global__ __launch_bounds__(256) void mgemm(const ushort* __restrict__ A,
                                             const ushort* __restrict__ Bp,
                                             const float* __restrict__ bias,
                                             ushort* __restrict__ Ch) {
    constexpr int K032 = K / 32;
    __shared__ ushort Bs[8 * K032 * 64 * 8];
    const int tid = threadIdx.x;
    for (int i = tid; i < K * 16; i += 256)
        ((float4*)Bs)[i] = ((const float4*)Bp)[i];
    const int lane = tid & 63, wave = tid >> 6;
    const int quad = lane >> 4, l15 = lane & 15;
    const int ch = wave & 1, rg = wave >> 1;
    __syncthreads();
    short8 breg[4][K032];
#pragma unroll
    for (int tt = 0; tt < 4; tt++)
#pragma unroll
        for (int k0 = 0; k0 < K032; k0++)
            breg[tt][k0] = *(const short8*)&Bs[(size_t)(((ch * 4 + tt) * K032 + k0) * 64 + lane) * 8];
    float bv[4] = {0.f, 0.f, 0.f, 0.f};
    if (bias)
#pragma unroll
        for (int tt = 0; tt < 4; tt++) bv[tt] = bias[(ch * 4 + tt) * 16 + l15];
    for (int tile = blockIdx.x; tile < NN / 32; tile += gridDim.x) {
        const int row0 = tile * 32 + rg * 16;
        const ushort* Ar = A + (size_t)(row0 + l15) * K + quad * 8;
        short8 a[K032];
#pragma unroll
        for (int k0 = 0; k0 < K032; k0++) a[k0] = *(const short8*)(Ar + k0 * 32);
        f32x4 acc[4];
#pragma unroll
        for (int tt = 0; tt < 4; tt++) acc[tt] = (f32x4){bv[tt], bv[tt], bv[tt], bv[tt]};
#pragma unroll
        for (int k0 = 0; k0 < K032; k0++)
#pragma unroll
            for (int tt = 0; tt < 4; tt++)
                acc[tt] = __builtin_amdgcn_mfma_f32_16x16x32_bf16(a[k0], breg[tt][k0], acc[tt], 0, 0, 0);
#pragma unroll
        for (int tt = 0; tt < 4; tt++) {
            const int col = (ch * 4 + tt) * 16 + l15;
#pragma unroll
            for (int r = 0; r < 4; r++) {
                ushort v = f2b(acc[tt][r]);
                if (MODE == 1) v = enc16(v);
                Ch[(size_t)(row0 + quad * 4 + r) * D + col] = v;
            }
        }
    }
}

// ---------------- fused per-layer GEMM: blockIdx.y = matrix (0=root, 1..4=conv r) ----------------
__global__ __launch_bounds__(256) void mgemm5(const ushort* __restrict__ A,
                                              const ushort* __restrict__ wpRootL,
                                              const ushort* __restrict__ wpConvL,
                                              const float* __restrict__ biasL,
                                              ushort* __restrict__ ob,
                                              ushort* __restrict__ mbuf) {
    constexpr int K032 = 4;  // K=128
    const int m = blockIdx.y;
    const ushort* Bp = (m == 0) ? wpRootL : wpConvL + (size_t)(m - 1) * 128 * 128;
    ushort* Ch = (m == 0) ? ob : mbuf + (size_t)(m - 1) * NN * D;
    const bool key = (m != 0);
    __shared__ ushort Bs[8 * K032 * 64 * 8];
    const int tid = threadIdx.x;
    for (int i = tid; i < 128 * 16; i += 256)
        ((float4*)Bs)[i] = ((const float4*)Bp)[i];
    const int lane = tid & 63, wave = tid >> 6;
    const int quad = lane >> 4, l15 = lane & 15;
    const int ch = wave & 1, rg = wave >> 1;
    __syncthreads();
    short8 breg[4][K032];
#pragma unroll
    for (int tt = 0; tt < 4; tt++)
#pragma unroll
        for (int k0 = 0; k0 < K032; k0++)
            breg[tt][k0] = *(const short8*)&Bs[(size_t)(((ch * 4 + tt) * K032 + k0) * 64 + lane) * 8];
    float bv[4] = {0.f, 0.f, 0.f, 0.f};
    if (m == 0)
#pragma unroll
        for (int tt = 0; tt < 4; tt++) bv[tt] = biasL[(ch * 4 + tt) * 16 + l15];
    for (int tile = blockIdx.x; tile < NN / 32; tile += gridDim.x) {
        const int row0 = tile * 32 + rg * 16;
        const ushort* Ar = A + (size_t)(row0 + l15) * 128 + quad * 8;
        short8 a[K032];
#pragma unroll
        for (int k0 = 0; k0 < K032; k0++) a[k0] = *(const short8*)(Ar + k0 * 32);
        f32x4 acc[4];
#pragma unroll
        for (int tt = 0; tt < 4; tt++) acc[tt] = (f32x4){bv[tt], bv[tt], bv[tt], bv[tt]};
#pragma unroll
        for (int k0 = 0; k0 < K032; k0++)
#pragma unroll
            for (int tt = 0; tt < 4; tt++)
                acc[tt] = __builtin_amdgcn_mfma_f32_16x16x32_bf16(a[k0], breg[tt][k0], acc[tt], 0, 0, 0);
#pragma unroll
        for (int tt = 0; tt < 4; tt++) {
            const int col = (ch * 4 + tt) * 16 + l15;
#pragma unroll
            for (int r = 0; r < 4; r++) {
                ushort v = f2b(acc[tt][r]);
                if (key) v = enc16(v);
                Ch[(size_t)(row0 + quad * 4 + r) * D + col] = v;
            }
        }
    }
}

// ---------------- fused multi-relation scatter-max over key16 messages ----------------
template <int CAP>
__global__ __launch_bounds__(256) void agg_kernel(const ushort* __restrict__ mb,
                                                  const int* __restrict__ deg,
                                                  const int* __restrict__ slots,
                                                  int G,
                                                  const ushort* __restrict__ base,
                                                  ushort* __restrict__ outh,
                                                  int do_relu) {
    int wv = threadIdx.x >> 6;
    int lane = threadIdx.x & 63;
    int node = blockIdx.x * 4 + wv;
    if (node >= NN) return;
    uint bp = ((const uint*)(base + (size_t)node * D))[lane];
    float rx = __uint_as_float(bp << 16), ry = __uint_as_float(bp & 0xffff0000u);
    for (int g = 0; g < G; g++) {
        const char* ml = (const char*)(mb + (size_t)g * NN * D) + lane * 4;
        const int* sl = slots + ((size_t)g * NN + node) * CAP;
        int nd = deg[(size_t)g * NN + node];
        if (nd > CAP) nd = CAP;
        if (nd <= 0) continue;
        u16x2 a0 = (u16x2)0, a1 = (u16x2)0, a2 = (u16x2)0, a3 = (u16x2)0;
        int s_l = (lane < nd) ? sl[lane] : 0;
        int i = 0;
        for (; i + 4 <= nd; i += 4) {
            int s0 = __shfl(s_l, i + 0);
            int s1 = __shfl(s_l, i + 1);
            int s2 = __shfl(s_l, i + 2);
            int s3 = __shfl(s_l, i + 3);
            u16x2 v0 = *(const u16x2*)(ml + s0);
            u16x2 v1 = *(const u16x2*)(ml + s1);
            u16x2 v2 = *(const u16x2*)(ml + s2);
            u16x2 v3 = *(const u16x2*)(ml + s3);
            a0 = vmax2(a0, v0);
            a1 = vmax2(a1, v1);
            a2 = vmax2(a2, v2);
            a3 = vmax2(a3, v3);
        }
        for (; i < nd; i++) {
            int s = __shfl(s_l, i);
            a0 = vmax2(a0, *(const u16x2*)(ml + s));
        }
        u16x2 am = vmax2(vmax2(a0, a1), vmax2(a2, a3));
        rx += b2f(dec16(am.x));
        ry += b2f(dec16(am.y));
    }
    if (do_relu) { rx = fmaxf(rx, 0.f); ry = fmaxf(ry, 0.f); }
    uint pk = (uint)f2b(rx) | ((uint)f2b(ry) << 16);
    ((uint*)(outh + (size_t)node * D))[lane] = pk;
}

// ---------------- global add pool (batch sorted), h in bf16 ----------------
#define PCH 256
__global__ __launch_bounds__(128) void pool_kernel(const ushort* __restrict__ h,
                                                   const int* __restrict__ batch,
                                                   float* __restrict__ out) {
    int c = threadIdx.x;
    int n0 = blockIdx.x * PCH;
    if (n0 >= NN) return;
    int n1 = n0 + PCH; if (n1 > NN) n1 = NN;
    int cur = batch[n0];
    float acc = 0.f;
    for (int n = n0; n < n1; n++) {
        int g = batch[n];
        if (g != cur) {
            atomicAdd(&out[cur * D + c], acc);
            acc = 0.f;
            cur = g;
        }
        acc += b2f(h[(size_t)n * D + c]);
    }
    atomicAdd(&out[cur * D + c], acc);
}

extern "C" void kernel_launch(void* const* d_in, const int* in_sizes, int n_in,
                              void* d_out, int out_size, void* d_ws, size_t ws_size,
                              hipStream_t stream) {
    const float* x = (const float*)d_in[0];
    const int* ei[4] = {(const int*)d_in[1], (const int*)d_in[2],
                        (const int*)d_in[3], (const int*)d_in[4]};
    const int* batch = (const int*)d_in[5];
    const float* emb_w = (const float*)d_in[6];
    const float* emb_b = (const float*)d_in[7];
    const float* root_w = (const float*)d_in[8];
    const float* root_b = (const float*)d_in[9];
    const float* conv_w = (const float*)d_in[10];
    float* out = (float*)d_out;

    const size_t WPT = (size_t)FIN * 128 + 20 * (size_t)128 * 128;  // permuted weights
    // choose (G, CAP) by ws capacity (ws_size constant across calls -> same path every launch)
    int G = 1, CAP = 32;
    {
        struct Cfg { int g, cap; } cfgs[] = {{4, 64}, {4, 32}, {2, 32}, {1, 32}};
        for (auto c : cfgs) {
            size_t need = ((size_t)NN * D * (2 + c.g) + (size_t)NN * FIN + WPT) * 2 +
                          ((size_t)NR * NN * (1 + c.cap)) * 4;
            if (ws_size >= need) { G = c.g; CAP = c.cap; break; }
        }
    }

    // workspace layout
    ushort* hb = (ushort*)d_ws;                        // NN*D
    ushort* ob = hb + (size_t)NN * D;                  // NN*D (base)
    ushort* mbuf = ob + (size_t)NN * D;                // G*NN*D (key16)
    ushort* xb = mbuf + (size_t)G * NN * D;            // NN*FIN
    ushort* wp = xb + (size_t)NN * FIN;                // WPT
    int* deg = (int*)(wp + WPT);                       // NR*NN
    int* slots = deg + (size_t)NR * NN;                // NR*NN*CAP (src byte-offsets)
    ushort* wpEmb = wp;
    ushort* wpRoot = wp + (size_t)FIN * 128;
    ushort* wpConv = wpRoot + (size_t)4 * 128 * 128;

    // ---- adjacency build: zero deg + one-pass partitioned slot fill ----
    zero_i32<<<(NR * NN + 255) / 256, 256, 0, stream>>>(deg, NR * NN);
    {
        int nch = (NR * NE + EPB - 1) / EPB;
        if (CAP == 64)
            slot_fill<64><<<nch * FP, 256, 0, stream>>>(ei[0], ei[1], ei[2], ei[3], deg, slots);
        else
            slot_fill<32><<<nch * FP, 256, 0, stream>>>(ei[0], ei[1], ei[2], ei[3], deg, slots);
    }

    // ---- weight permute + input convert ----
    {
        int t1 = FIN * 128;
        wperm_kernel<<<(t1 + 255) / 256, 256, 0, stream>>>(emb_w, wpEmb, FIN, t1);
        int t2 = 4 * 128 * 128;
        wperm_kernel<<<(t2 + 255) / 256, 256, 0, stream>>>(root_w, wpRoot, 128, t2);
        int t3 = 16 * 128 * 128;
        wperm_kernel<<<(t3 + 255) / 256, 256, 0, stream>>>(conv_w, wpConv, 128, t3);
        int t4 = NN * FIN;
        xcvt<<<(t4 + 255) / 256, 256, 0, stream>>>(x, xb, t4);
    }

    // ---- embedding ----
    mgemm<FIN, 0><<<1024, 256, 0, stream>>>(xb, wpEmb, emb_b, hb);

    // ---- layers ----
    for (int l = 0; l < NL; l++) {
        if (G == 4) {
            mgemm5<<<dim3(640, 5), 256, 0, stream>>>(hb, wpRoot + (size_t)l * 128 * 128,
                                                     wpConv + (size_t)l * 4 * 128 * 128,
                                                     root_b + (size_t)l * D, ob, mbuf);
            if (CAP == 64)
                agg_kernel<64><<<(NN + 3) / 4, 256, 0, stream>>>(mbuf, deg, slots, 4, ob, hb, 1);
            else
                agg_kernel<32><<<(NN + 3) / 4, 256, 0, stream>>>(mbuf, deg, slots, 4, ob, hb, 1);
        } else {
            mgemm<128, 0><<<1024, 256, 0, stream>>>(hb, wpRoot + (size_t)l * 128 * 128,
                                                    root_b + (size_t)l * D, ob);
            for (int g0 = 0; g0 < NR; g0 += G) {
                for (int r = g0; r < g0 + G; r++)
                    mgemm<128, 1><<<1024, 256, 0, stream>>>(
                        hb, wpConv + (size_t)(l * NR + r) * 128 * 128, nullptr,
                        mbuf + (size_t)(r - g0) * NN * D);
                int last = (g0 + G == NR);
                agg_kernel<32><<<(NN + 3) / 4, 256, 0, stream>>>(
                    mbuf, deg + (size_t)g0 * NN, slots + (size_t)g0 * NN * 32, G,
                    ob, last ? hb : ob, last ? 1 : 0);
            }
        }
    }

    // ---- global add pool ----
    zero_f32<<<(NGR * D + 255) / 256, 256, 0, stream>>>(out, NGR * D);
    pool_kernel<<<(NN + PCH - 1) / PCH, 128, 0, stream>>>(hb, batch, out);
}

// Round 7
// 860.356 us; speedup vs baseline: 1.3062x; 1.1011x over previous
//
#include <hip/hip_runtime.h>

#define NN 100000   // nodes
#define NE 500000   // edges per relation
#define NR 4        // relations
#define NL 4        // layers
#define FIN 64      // input features
#define D 128       // embedding dim
#define NGR 64      // graphs

#define FP 8        // dst partitions (XCD round-robin heuristic)
#define PSZ ((NN + FP - 1) / FP)   // 12500 nodes per partition
#define EPB 4096    // edges per block chunk in slot_fill
#define CAPS 32     // slot capacity (P(deg>32 | Poisson(5)) ~ 1e-15)

typedef __attribute__((ext_vector_type(8))) short short8;
typedef __attribute__((ext_vector_type(4))) float f32x4;
typedef __attribute__((ext_vector_type(2))) unsigned short u16x2;
typedef unsigned short ushort;
typedef unsigned int uint;

__device__ __forceinline__ ushort f2b(float f) {
    uint u = __float_as_uint(f);
    uint r = (u + 0x7fffu + ((u >> 16) & 1u)) >> 16;  // RNE
    return (ushort)r;
}
__device__ __forceinline__ float b2f(ushort b) {
    return __uint_as_float(((uint)b) << 16);
}
// monotone bf16 -> u16 key (order-isomorphic bijection); key 0 = -inf sentinel
__device__ __forceinline__ ushort enc16(ushort u) {
    return u ^ (ushort)((((short)u) >> 15) | (short)0x8000);
}
__device__ __forceinline__ ushort dec16(ushort k) {
    return k ^ (ushort)((((short)(k ^ 0x8000)) >> 15) | (short)0x8000);
}
__device__ __forceinline__ u16x2 vmax2(u16x2 a, u16x2 b) {
#if __has_builtin(__builtin_elementwise_max)
    return __builtin_elementwise_max(a, b);
#else
    u16x2 r;
    r.x = a.x > b.x ? a.x : b.x;
    r.y = a.y > b.y ? a.y : b.y;
    return r;
#endif
}

// ---------------- utility ----------------
__global__ void zero_i32(int* __restrict__ p, int n) {
    int i = blockIdx.x * blockDim.x + threadIdx.x;
    if (i < n) p[i] = 0;
}
__global__ void zero_f32(float* __restrict__ p, int n) {
    int i = blockIdx.x * blockDim.x + threadIdx.x;
    if (i < n) p[i] = 0.f;
}
__global__ void xcvt(const float* __restrict__ x, ushort* __restrict__ xb, int n) {
    int i = blockIdx.x * blockDim.x + threadIdx.x;
    if (i < n) xb[i] = f2b(x[i]);
}
// zero the dummy row (index NN) of each of the G m-buffers (stride (NN+1)*D)
__global__ void zero_dummy(ushort* __restrict__ mbuf, int G) {
    int i = blockIdx.x * blockDim.x + threadIdx.x;
    if (i < G * D)
        mbuf[(size_t)(i / D) * (NN + 1) * D + (size_t)NN * D + (i % D)] = 0;
}

// W fp32 [nmat][K x 128] -> bf16 MFMA B-fragment order
__global__ void wperm_kernel(const float* __restrict__ W, ushort* __restrict__ dst,
                             int K, int total) {
    int i = blockIdx.x * blockDim.x + threadIdx.x;
    if (i >= total) return;
    int per = K * 128;
    int mi = i / per;
    int o = i - mi * per;
    int j = o & 7, lane = (o >> 3) & 63, rest = o >> 9;
    int K032 = K / 32;
    int k0 = rest % K032, t = rest / K032;
    int k = k0 * 32 + (lane >> 4) * 8 + j;
    int n = t * 16 + (lane & 15);
    dst[i] = f2b(W[(size_t)mi * per + k * 128 + n]);
}

// ---------------- one-pass slotted adjacency build, XCD-partitioned ----------------
// deg[node*NR + r]; slots[(node*NR + r)*CAPS + slot] = src byte-offset.
__global__ __launch_bounds__(256) void slot_fill(const int* __restrict__ e0,
                                                 const int* __restrict__ e1,
                                                 const int* __restrict__ e2,
                                                 const int* __restrict__ e3,
                                                 int* __restrict__ deg,
                                                 int* __restrict__ slots) {
    const int part = blockIdx.x % FP;
    const int chunk = blockIdx.x / FP;
    const int plo = part * PSZ;
    const int phi = (plo + PSZ < NN) ? plo + PSZ : NN;
    const int i0 = chunk * EPB;
    int i1 = i0 + EPB; if (i1 > NR * NE) i1 = NR * NE;
    for (int i = i0 + threadIdx.x; i < i1; i += 256) {
        int r = i / NE, j = i - r * NE;
        const int* ei = (r == 0) ? e0 : (r == 1) ? e1 : (r == 2) ? e2 : e3;
        int d = ei[NE + j];
        if (d >= plo && d < phi) {
            int s = ei[j];
            int slot = atomicAdd(&deg[d * NR + r], 1);
            if (slot < CAPS)
                slots[((size_t)d * NR + r) * CAPS + slot] = s * (D * 2);
        }
    }
}

// ---------------- bf16 MFMA GEMM (embedding / fallback) ----------------
template <int K, int MODE>
__global__ __launch_bounds__(256) void mgemm(const ushort* __restrict__ A,
                                             const ushort* __restrict__ Bp,
                                             const float* __restrict__ bias,
                                             ushort* __restrict__ Ch) {
    constexpr int K032 = K / 32;
    __shared__ ushort Bs[8 * K032 * 64 * 8];
    const int tid = threadIdx.x;
    for (int i = tid; i < K * 16; i += 256)
        ((float4*)Bs)[i] = ((const float4*)Bp)[i];
    const int lane = tid & 63, wave = tid >> 6;
    const int quad = lane >> 4, l15 = lane & 15;
    const int ch = wave & 1, rg = wave >> 1;
    __syncthreads();
    short8 breg[4][K032];
#pragma unroll
    for (int tt = 0; tt < 4; tt++)
#pragma unroll
        for (int k0 = 0; k0 < K032; k0++)
            breg[tt][k0] = *(const short8*)&Bs[(size_t)(((ch * 4 + tt) * K032 + k0) * 64 + lane) * 8];
    float bv[4] = {0.f, 0.f, 0.f, 0.f};
    if (bias)
#pragma unroll
        for (int tt = 0; tt < 4; tt++) bv[tt] = bias[(ch * 4 + tt) * 16 + l15];
    for (int tile = blockIdx.x; tile < NN / 32; tile += gridDim.x) {
        const int row0 = tile * 32 + rg * 16;
        const ushort* Ar = A + (size_t)(row0 + l15) * K + quad * 8;
        short8 a[K032];
#pragma unroll
        for (int k0 = 0; k0 < K032; k0++) a[k0] = *(const short8*)(Ar + k0 * 32);
        f32x4 acc[4];
#pragma unroll
        for (int tt = 0; tt < 4; tt++) acc[tt] = (f32x4){bv[tt], bv[tt], bv[tt], bv[tt]};
#pragma unroll
        for (int k0 = 0; k0 < K032; k0++)
#pragma unroll
            for (int tt = 0; tt < 4; tt++)
                acc[tt] = __builtin_amdgcn_mfma_f32_16x16x32_bf16(a[k0], breg[tt][k0], acc[tt], 0, 0, 0);
#pragma unroll
        for (int tt = 0; tt < 4; tt++) {
            const int col = (ch * 4 + tt) * 16 + l15;
#pragma unroll
            for (int r = 0; r < 4; r++) {
                ushort v = f2b(acc[tt][r]);
                if (MODE == 1) v = enc16(v);
                Ch[(size_t)(row0 + quad * 4 + r) * D + col] = v;
            }
        }
    }
}

// ---------------- fused per-layer GEMM: blockIdx.y = matrix (0=root, 1..4=conv r) ----------------
__global__ __launch_bounds__(256) void mgemm5(const ushort* __restrict__ A,
                                              const ushort* __restrict__ wpRootL,
                                              const ushort* __restrict__ wpConvL,
                                              const float* __restrict__ biasL,
                                              ushort* __restrict__ ob,
                                              ushort* __restrict__ mbuf) {
    constexpr int K032 = 4;  // K=128
    const int m = blockIdx.y;
    const ushort* Bp = (m == 0) ? wpRootL : wpConvL + (size_t)(m - 1) * 128 * 128;
    ushort* Ch = (m == 0) ? ob : mbuf + (size_t)(m - 1) * (NN + 1) * D;
    const bool key = (m != 0);
    __shared__ ushort Bs[8 * K032 * 64 * 8];
    const int tid = threadIdx.x;
    for (int i = tid; i < 128 * 16; i += 256)
        ((float4*)Bs)[i] = ((const float4*)Bp)[i];
    const int lane = tid & 63, wave = tid >> 6;
    const int quad = lane >> 4, l15 = lane & 15;
    const int ch = wave & 1, rg = wave >> 1;
    __syncthreads();
    short8 breg[4][K032];
#pragma unroll
    for (int tt = 0; tt < 4; tt++)
#pragma unroll
        for (int k0 = 0; k0 < K032; k0++)
            breg[tt][k0] = *(const short8*)&Bs[(size_t)(((ch * 4 + tt) * K032 + k0) * 64 + lane) * 8];
    float bv[4] = {0.f, 0.f, 0.f, 0.f};
    if (m == 0)
#pragma unroll
        for (int tt = 0; tt < 4; tt++) bv[tt] = biasL[(ch * 4 + tt) * 16 + l15];
    for (int tile = blockIdx.x; tile < NN / 32; tile += gridDim.x) {
        const int row0 = tile * 32 + rg * 16;
        const ushort* Ar = A + (size_t)(row0 + l15) * 128 + quad * 8;
        short8 a[K032];
#pragma unroll
        for (int k0 = 0; k0 < K032; k0++) a[k0] = *(const short8*)(Ar + k0 * 32);
        f32x4 acc[4];
#pragma unroll
        for (int tt = 0; tt < 4; tt++) acc[tt] = (f32x4){bv[tt], bv[tt], bv[tt], bv[tt]};
#pragma unroll
        for (int k0 = 0; k0 < K032; k0++)
#pragma unroll
            for (int tt = 0; tt < 4; tt++)
                acc[tt] = __builtin_amdgcn_mfma_f32_16x16x32_bf16(a[k0], breg[tt][k0], acc[tt], 0, 0, 0);
#pragma unroll
        for (int tt = 0; tt < 4; tt++) {
            const int col = (ch * 4 + tt) * 16 + l15;
#pragma unroll
            for (int r = 0; r < 4; r++) {
                ushort v = f2b(acc[tt][r]);
                if (key) v = enc16(v);
                Ch[(size_t)(row0 + quad * 4 + r) * D + col] = v;
            }
        }
    }
}

// ---------------- interleaved multi-relation scatter-max, G unrolled at compile time ----------------
// mb: G buffers of (NN+1)*D key16; row NN of each = zeroed dummy (-inf keys).
// Invalid (g,i) gathers are redirected to the dummy row -> branchless, max-neutral.
template <int G>
__global__ __launch_bounds__(256) void agg_kernel(const ushort* __restrict__ mb,
                                                  const int* __restrict__ deg,
                                                  const int* __restrict__ slots,
                                                  int g0,
                                                  const ushort* __restrict__ base,
                                                  ushort* __restrict__ outh,
                                                  int do_relu) {
    const int wv = threadIdx.x >> 6;
    const int lane = threadIdx.x & 63;
    const int node = blockIdx.x * 4 + wv;
    if (node >= NN) return;
    const int DUM = NN * D * 2;  // byte offset of dummy row
    const int* db = deg + (size_t)node * NR + g0;
    const int* sb = slots + ((size_t)node * NR + g0) * CAPS;
    int nd[G], s_l[G];
    const char* ml[G];
#pragma unroll
    for (int g = 0; g < G; g++) {
        int n = db[g];
        nd[g] = (n > CAPS) ? CAPS : n;
        s_l[g] = (lane < nd[g]) ? sb[g * CAPS + lane] : DUM;
        ml[g] = (const char*)(mb + (size_t)g * (NN + 1) * D) + lane * 4;
    }
    int ndmax = 0;
#pragma unroll
    for (int g = 0; g < G; g++) ndmax = (nd[g] > ndmax) ? nd[g] : ndmax;
    u16x2 acc[G];
#pragma unroll
    for (int g = 0; g < G; g++) acc[g] = (u16x2)0;
    for (int i = 0; i < ndmax; i += 2) {
#pragma unroll
        for (int g = 0; g < G; g++) {
            int sa = __shfl(s_l[g], i);
            int sc = __shfl(s_l[g], i + 1);
            sa = (i < nd[g]) ? sa : DUM;
            sc = (i + 1 < nd[g]) ? sc : DUM;
            u16x2 va = *(const u16x2*)(ml[g] + sa);
            u16x2 vb = *(const u16x2*)(ml[g] + sc);
            acc[g] = vmax2(acc[g], vmax2(va, vb));
        }
    }
    uint bp = ((const uint*)(base + (size_t)node * D))[lane];
    float rx = __uint_as_float(bp << 16), ry = __uint_as_float(bp & 0xffff0000u);
#pragma unroll
    for (int g = 0; g < G; g++) {
        rx += (nd[g] > 0) ? b2f(dec16(acc[g].x)) : 0.f;
        ry += (nd[g] > 0) ? b2f(dec16(acc[g].y)) : 0.f;
    }
    if (do_relu) { rx = fmaxf(rx, 0.f); ry = fmaxf(ry, 0.f); }
    uint pk = (uint)f2b(rx) | ((uint)f2b(ry) << 16);
    ((uint*)(outh + (size_t)node * D))[lane] = pk;
}

// ---------------- global add pool (batch sorted), h in bf16 ----------------
#define PCH 256
__global__ __launch_bounds__(128) void pool_kernel(const ushort* __restrict__ h,
                                                   const int* __restrict__ batch,
                                                   float* __restrict__ out) {
    int c = threadIdx.x;
    int n0 = blockIdx.x * PCH;
    if (n0 >= NN) return;
    int n1 = n0 + PCH; if (n1 > NN) n1 = NN;
    int cur = batch[n0];
    float acc = 0.f;
    for (int n = n0; n < n1; n++) {
        int g = batch[n];
        if (g != cur) {
            atomicAdd(&out[cur * D + c], acc);
            acc = 0.f;
            cur = g;
        }
        acc += b2f(h[(size_t)n * D + c]);
    }
    atomicAdd(&out[cur * D + c], acc);
}

extern "C" void kernel_launch(void* const* d_in, const int* in_sizes, int n_in,
                              void* d_out, int out_size, void* d_ws, size_t ws_size,
                              hipStream_t stream) {
    const float* x = (const float*)d_in[0];
    const int* ei[4] = {(const int*)d_in[1], (const int*)d_in[2],
                        (const int*)d_in[3], (const int*)d_in[4]};
    const int* batch = (const int*)d_in[5];
    const float* emb_w = (const float*)d_in[6];
    const float* emb_b = (const float*)d_in[7];
    const float* root_w = (const float*)d_in[8];
    const float* root_b = (const float*)d_in[9];
    const float* conv_w = (const float*)d_in[10];
    float* out = (float*)d_out;

    const size_t WPT = (size_t)FIN * 128 + 20 * (size_t)128 * 128;  // permuted weights
    // choose G by ws capacity (ws_size constant across calls -> same path every launch)
    int G = 1;
    for (int g = 4; g >= 1; g >>= 1) {
        size_t need = ((size_t)NN * D * 2 + (size_t)g * (NN + 1) * D + (size_t)NN * FIN + WPT) * 2 +
                      ((size_t)NR * NN * (1 + CAPS)) * 4;
        if (ws_size >= need) { G = g; break; }
    }

    // workspace layout
    ushort* hb = (ushort*)d_ws;                          // NN*D
    ushort* ob = hb + (size_t)NN * D;                    // NN*D (base)
    ushort* mbuf = ob + (size_t)NN * D;                  // G*(NN+1)*D (key16, +dummy row)
    ushort* xb = mbuf + (size_t)G * (NN + 1) * D;        // NN*FIN
    ushort* wp = xb + (size_t)NN * FIN;                  // WPT
    int* deg = (int*)(wp + WPT);                         // NN*NR  (node-major)
    int* slots = deg + (size_t)NR * NN;                  // NN*NR*CAPS (src byte-offsets)
    ushort* wpEmb = wp;
    ushort* wpRoot = wp + (size_t)FIN * 128;
    ushort* wpConv = wpRoot + (size_t)4 * 128 * 128;

    // ---- adjacency build: zero deg + one-pass partitioned slot fill ----
    zero_i32<<<(NR * NN + 255) / 256, 256, 0, stream>>>(deg, NR * NN);
    {
        int nch = (NR * NE + EPB - 1) / EPB;
        slot_fill<<<nch * FP, 256, 0, stream>>>(ei[0], ei[1], ei[2], ei[3], deg, slots);
    }

    // ---- weight permute + input convert + dummy rows ----
    {
        int t1 = FIN * 128;
        wperm_kernel<<<(t1 + 255) / 256, 256, 0, stream>>>(emb_w, wpEmb, FIN, t1);
        int t2 = 4 * 128 * 128;
        wperm_kernel<<<(t2 + 255) / 256, 256, 0, stream>>>(root_w, wpRoot, 128, t2);
        int t3 = 16 * 128 * 128;
        wperm_kernel<<<(t3 + 255) / 256, 256, 0, stream>>>(conv_w, wpConv, 128, t3);
        int t4 = NN * FIN;
        xcvt<<<(t4 + 255) / 256, 256, 0, stream>>>(x, xb, t4);
        zero_dummy<<<(G * D + 255) / 256, 256, 0, stream>>>(mbuf, G);
    }

    // ---- embedding ----
    mgemm<FIN, 0><<<1024, 256, 0, stream>>>(xb, wpEmb, emb_b, hb);

    // ---- layers ----
    for (int l = 0; l < NL; l++) {
        if (G == 4) {
            mgemm5<<<dim3(640, 5), 256, 0, stream>>>(hb, wpRoot + (size_t)l * 128 * 128,
                                                     wpConv + (size_t)l * 4 * 128 * 128,
                                                     root_b + (size_t)l * D, ob, mbuf);
            agg_kernel<4><<<(NN + 3) / 4, 256, 0, stream>>>(mbuf, deg, slots, 0, ob, hb, 1);
        } else {
            mgemm<128, 0><<<1024, 256, 0, stream>>>(hb, wpRoot + (size_t)l * 128 * 128,
                                                    root_b + (size_t)l * D, ob);
            for (int g0 = 0; g0 < NR; g0 += G) {
                for (int r = g0; r < g0 + G; r++)
                    mgemm<128, 1><<<1024, 256, 0, stream>>>(
                        hb, wpConv + (size_t)(l * NR + r) * 128 * 128, nullptr,
                        mbuf + (size_t)(r - g0) * (NN + 1) * D);
                int last = (g0 + G == NR);
                if (G == 2)
                    agg_kernel<2><<<(NN + 3) / 4, 256, 0, stream>>>(
                        mbuf, deg, slots, g0, ob, last ? hb : ob, last ? 1 : 0);
                else
                    agg_kernel<1><<<(NN + 3) / 4, 256, 0, stream>>>(
                        mbuf, deg, slots, g0, ob, last ? hb : ob, last ? 1 : 0);
            }
        }
    }

    // ---- global add pool ----
    zero_f32<<<(NGR * D + 255) / 256, 256, 0, stream>>>(out, NGR * D);
    pool_kernel<<<(NN + PCH - 1) / PCH, 128, 0, stream>>>(hb, batch, out);
}

// Round 8
// 848.832 us; speedup vs baseline: 1.3239x; 1.0136x over previous
//
#include <hip/hip_runtime.h>

#define NN 100000   // nodes
#define NE 500000   // edges per relation
#define NR 4        // relations
#define NL 4        // layers
#define FIN 64      // input features
#define D 128       // embedding dim
#define NGR 64      // graphs

#define FP 8        // dst partitions (XCD round-robin heuristic)
#define PSZ ((NN + FP - 1) / FP)   // 12500 nodes per partition
#define EPB 4096    // edges per block chunk in slot_fill
#define CAPS 32     // slot capacity (P(deg>32 | Poisson(5)) ~ 1e-15)

typedef __attribute__((ext_vector_type(8))) short short8;
typedef __attribute__((ext_vector_type(4))) float f32x4;
typedef __attribute__((ext_vector_type(2))) unsigned short u16x2;
typedef unsigned short ushort;
typedef unsigned int uint;

__device__ __forceinline__ ushort f2b(float f) {
    uint u = __float_as_uint(f);
    uint r = (u + 0x7fffu + ((u >> 16) & 1u)) >> 16;  // RNE
    return (ushort)r;
}
__device__ __forceinline__ float b2f(ushort b) {
    return __uint_as_float(((uint)b) << 16);
}
// monotone bf16 -> u16 key (order-isomorphic bijection); key 0 = -inf sentinel
__device__ __forceinline__ ushort enc16(ushort u) {
    return u ^ (ushort)((((short)u) >> 15) | (short)0x8000);
}
__device__ __forceinline__ ushort dec16(ushort k) {
    return k ^ (ushort)((((short)(k ^ 0x8000)) >> 15) | (short)0x8000);
}
__device__ __forceinline__ u16x2 vmax2(u16x2 a, u16x2 b) {
#if __has_builtin(__builtin_elementwise_max)
    return __builtin_elementwise_max(a, b);
#else
    u16x2 r;
    r.x = a.x > b.x ? a.x : b.x;
    r.y = a.y > b.y ? a.y : b.y;
    return r;
#endif
}

// ---------------- utility ----------------
__global__ void zero_i32(int* __restrict__ p, int n) {
    int i = blockIdx.x * blockDim.x + threadIdx.x;
    if (i < n) p[i] = 0;
}
__global__ void zero_f32(float* __restrict__ p, int n) {
    int i = blockIdx.x * blockDim.x + threadIdx.x;
    if (i < n) p[i] = 0.f;
}
__global__ void xcvt(const float* __restrict__ x, ushort* __restrict__ xb, int n) {
    int i = blockIdx.x * blockDim.x + threadIdx.x;
    if (i < n) xb[i] = f2b(x[i]);
}
// zero the dummy row (index NN) of each of the G m-buffers (stride (NN+1)*D)
__global__ void zero_dummy(ushort* __restrict__ mbuf, int G) {
    int i = blockIdx.x * blockDim.x + threadIdx.x;
    if (i < G * D)
        mbuf[(size_t)(i / D) * (NN + 1) * D + (size_t)NN * D + (i % D)] = 0;
}

// W fp32 [nmat][K x 128] -> bf16 MFMA B-fragment order
__global__ void wperm_kernel(const float* __restrict__ W, ushort* __restrict__ dst,
                             int K, int total) {
    int i = blockIdx.x * blockDim.x + threadIdx.x;
    if (i >= total) return;
    int per = K * 128;
    int mi = i / per;
    int o = i - mi * per;
    int j = o & 7, lane = (o >> 3) & 63, rest = o >> 9;
    int K032 = K / 32;
    int k0 = rest % K032, t = rest / K032;
    int k = k0 * 32 + (lane >> 4) * 8 + j;
    int n = t * 16 + (lane & 15);
    dst[i] = f2b(W[(size_t)mi * per + k * 128 + n]);
}

// ---------------- one-pass slotted adjacency build, XCD-partitioned ----------------
// deg[node*NR + r]; slots[(node*NR + r)*CAPS + slot] = src byte-offset.
// Edge arrays are streamed with NONTEMPORAL loads so they don't evict the
// partially-filled slot lines from L2 (write-amplification fix).
__global__ __launch_bounds__(256) void slot_fill(const int* __restrict__ e0,
                                                 const int* __restrict__ e1,
                                                 const int* __restrict__ e2,
                                                 const int* __restrict__ e3,
                                                 int* __restrict__ deg,
                                                 int* __restrict__ slots) {
    const int part = blockIdx.x % FP;
    const int chunk = blockIdx.x / FP;
    const int plo = part * PSZ;
    const int phi = (plo + PSZ < NN) ? plo + PSZ : NN;
    const int i0 = chunk * EPB;
    int i1 = i0 + EPB; if (i1 > NR * NE) i1 = NR * NE;
    for (int i = i0 + threadIdx.x; i < i1; i += 256) {
        int r = i / NE, j = i - r * NE;
        const int* ei = (r == 0) ? e0 : (r == 1) ? e1 : (r == 2) ? e2 : e3;
        int d = __builtin_nontemporal_load(&ei[NE + j]);
        if (d >= plo && d < phi) {
            int s = __builtin_nontemporal_load(&ei[j]);
            int slot = atomicAdd(&deg[d * NR + r], 1);
            if (slot < CAPS)
                slots[((size_t)d * NR + r) * CAPS + slot] = s * (D * 2);
        }
    }
}

// ---------------- bf16 MFMA GEMM (embedding / fallback) ----------------
template <int K, int MODE>
__global__ __launch_bounds__(256) void mgemm(const ushort* __restrict__ A,
                                             const ushort* __restrict__ Bp,
                                             const float* __restrict__ bias,
                                             ushort* __restrict__ Ch) {
    constexpr int K032 = K / 32;
    __shared__ ushort Bs[8 * K032 * 64 * 8];
    const int tid = threadIdx.x;
    for (int i = tid; i < K * 16; i += 256)
        ((float4*)Bs)[i] = ((const float4*)Bp)[i];
    const int lane = tid & 63, wave = tid >> 6;
    const int quad = lane >> 4, l15 = lane & 15;
    const int ch = wave & 1, rg = wave >> 1;
    __syncthreads();
    short8 breg[4][K032];
#pragma unroll
    for (int tt = 0; tt < 4; tt++)
#pragma unroll
        for (int k0 = 0; k0 < K032; k0++)
            breg[tt][k0] = *(const short8*)&Bs[(size_t)(((ch * 4 + tt) * K032 + k0) * 64 + lane) * 8];
    float bv[4] = {0.f, 0.f, 0.f, 0.f};
    if (bias)
#pragma unroll
        for (int tt = 0; tt < 4; tt++) bv[tt] = bias[(ch * 4 + tt) * 16 + l15];
    for (int tile = blockIdx.x; tile < NN / 32; tile += gridDim.x) {
        const int row0 = tile * 32 + rg * 16;
        const ushort* Ar = A + (size_t)(row0 + l15) * K + quad * 8;
        short8 a[K032];
#pragma unroll
        for (int k0 = 0; k0 < K032; k0++) a[k0] = *(const short8*)(Ar + k0 * 32);
        f32x4 acc[4];
#pragma unroll
        for (int tt = 0; tt < 4; tt++) acc[tt] = (f32x4){bv[tt], bv[tt], bv[tt], bv[tt]};
#pragma unroll
        for (int k0 = 0; k0 < K032; k0++)
#pragma unroll
            for (int tt = 0; tt < 4; tt++)
                acc[tt] = __builtin_amdgcn_mfma_f32_16x16x32_bf16(a[k0], breg[tt][k0], acc[tt], 0, 0, 0);
#pragma unroll
        for (int tt = 0; tt < 4; tt++) {
            const int col = (ch * 4 + tt) * 16 + l15;
#pragma unroll
            for (int r = 0; r < 4; r++) {
                ushort v = f2b(acc[tt][r]);
                if (MODE == 1) v = enc16(v);
                Ch[(size_t)(row0 + quad * 4 + r) * D + col] = v;
            }
        }
    }
}

// ---------------- fused per-layer GEMM: blockIdx.y = matrix (0=root, 1..4=conv r) ----------------
__global__ __launch_bounds__(256) void mgemm5(const ushort* __restrict__ A,
                                              const ushort* __restrict__ wpRootL,
                                              const ushort* __restrict__ wpConvL,
                                              const float* __restrict__ biasL,
                                              ushort* __restrict__ ob,
                                              ushort* __restrict__ mbuf) {
    constexpr int K032 = 4;  // K=128
    const int m = blockIdx.y;
    const ushort* Bp = (m == 0) ? wpRootL : wpConvL + (size_t)(m - 1) * 128 * 128;
    ushort* Ch = (m == 0) ? ob : mbuf + (size_t)(m - 1) * (NN + 1) * D;
    const bool key = (m != 0);
    __shared__ ushort Bs[8 * K032 * 64 * 8];
    const int tid = threadIdx.x;
    for (int i = tid; i < 128 * 16; i += 256)
        ((float4*)Bs)[i] = ((const float4*)Bp)[i];
    const int lane = tid & 63, wave = tid >> 6;
    const int quad = lane >> 4, l15 = lane & 15;
    const int ch = wave & 1, rg = wave >> 1;
    __syncthreads();
    short8 breg[4][K032];
#pragma unroll
    for (int tt = 0; tt < 4; tt++)
#pragma unroll
        for (int k0 = 0; k0 < K032; k0++)
            breg[tt][k0] = *(const short8*)&Bs[(size_t)(((ch * 4 + tt) * K032 + k0) * 64 + lane) * 8];
    float bv[4] = {0.f, 0.f, 0.f, 0.f};
    if (m == 0)
#pragma unroll
        for (int tt = 0; tt < 4; tt++) bv[tt] = biasL[(ch * 4 + tt) * 16 + l15];
    for (int tile = blockIdx.x; tile < NN / 32; tile += gridDim.x) {
        const int row0 = tile * 32 + rg * 16;
        const ushort* Ar = A + (size_t)(row0 + l15) * 128 + quad * 8;
        short8 a[K032];
#pragma unroll
        for (int k0 = 0; k0 < K032; k0++) a[k0] = *(const short8*)(Ar + k0 * 32);
        f32x4 acc[4];
#pragma unroll
        for (int tt = 0; tt < 4; tt++) acc[tt] = (f32x4){bv[tt], bv[tt], bv[tt], bv[tt]};
#pragma unroll
        for (int k0 = 0; k0 < K032; k0++)
#pragma unroll
            for (int tt = 0; tt < 4; tt++)
                acc[tt] = __builtin_amdgcn_mfma_f32_16x16x32_bf16(a[k0], breg[tt][k0], acc[tt], 0, 0, 0);
#pragma unroll
        for (int tt = 0; tt < 4; tt++) {
            const int col = (ch * 4 + tt) * 16 + l15;
#pragma unroll
            for (int r = 0; r < 4; r++) {
                ushort v = f2b(acc[tt][r]);
                if (key) v = enc16(v);
                Ch[(size_t)(row0 + quad * 4 + r) * D + col] = v;
            }
        }
    }
}

// ---------------- interleaved multi-relation scatter-max, 4-wide unrolled ----------------
// mb: G buffers of (NN+1)*D key16; row NN of each = zeroed dummy (-inf keys).
// Invalid (g,i) gathers are redirected to the dummy row -> branchless, max-neutral.
template <int G>
__global__ __launch_bounds__(256) void agg_kernel(const ushort* __restrict__ mb,
                                                  const int* __restrict__ deg,
                                                  const int* __restrict__ slots,
                                                  int g0,
                                                  const ushort* __restrict__ base,
                                                  ushort* __restrict__ outh,
                                                  int do_relu) {
    const int wv = threadIdx.x >> 6;
    const int lane = threadIdx.x & 63;
    const int node = blockIdx.x * 4 + wv;
    if (node >= NN) return;
    const int DUM = NN * D * 2;  // byte offset of dummy row
    const int* db = deg + (size_t)node * NR + g0;
    const int* sb = slots + ((size_t)node * NR + g0) * CAPS;
    int nd[G], s_l[G];
    const char* ml[G];
#pragma unroll
    for (int g = 0; g < G; g++) {
        int n = db[g];
        nd[g] = (n > CAPS) ? CAPS : n;
        s_l[g] = (lane < nd[g]) ? sb[g * CAPS + lane] : DUM;
        ml[g] = (const char*)(mb + (size_t)g * (NN + 1) * D) + lane * 4;
    }
    int ndmax = 0;
#pragma unroll
    for (int g = 0; g < G; g++) ndmax = (nd[g] > ndmax) ? nd[g] : ndmax;
    u16x2 acc[G];
#pragma unroll
    for (int g = 0; g < G; g++) acc[g] = (u16x2)0;
    for (int i = 0; i < ndmax; i += 4) {
        int s[G][4];
#pragma unroll
        for (int g = 0; g < G; g++) {
#pragma unroll
            for (int u = 0; u < 4; u++) {
                int sv = __shfl(s_l[g], i + u);
                s[g][u] = (i + u < nd[g]) ? sv : DUM;
            }
        }
#pragma unroll
        for (int g = 0; g < G; g++) {
            u16x2 v0 = *(const u16x2*)(ml[g] + s[g][0]);
            u16x2 v1 = *(const u16x2*)(ml[g] + s[g][1]);
            u16x2 v2 = *(const u16x2*)(ml[g] + s[g][2]);
            u16x2 v3 = *(const u16x2*)(ml[g] + s[g][3]);
            acc[g] = vmax2(acc[g], vmax2(vmax2(v0, v1), vmax2(v2, v3)));
        }
    }
    uint bp = ((const uint*)(base + (size_t)node * D))[lane];
    float rx = __uint_as_float(bp << 16), ry = __uint_as_float(bp & 0xffff0000u);
#pragma unroll
    for (int g = 0; g < G; g++) {
        rx += (nd[g] > 0) ? b2f(dec16(acc[g].x)) : 0.f;
        ry += (nd[g] > 0) ? b2f(dec16(acc[g].y)) : 0.f;
    }
    if (do_relu) { rx = fmaxf(rx, 0.f); ry = fmaxf(ry, 0.f); }
    uint pk = (uint)f2b(rx) | ((uint)f2b(ry) << 16);
    ((uint*)(outh + (size_t)node * D))[lane] = pk;
}

// ---------------- global add pool (batch sorted), h in bf16 ----------------
#define PCH 256
__global__ __launch_bounds__(128) void pool_kernel(const ushort* __restrict__ h,
                                                   const int* __restrict__ batch,
                                                   float* __restrict__ out) {
    int c = threadIdx.x;
    int n0 = blockIdx.x * PCH;
    if (n0 >= NN) return;
    int n1 = n0 + PCH; if (n1 > NN) n1 = NN;
    int cur = batch[n0];
    float acc = 0.f;
    for (int n = n0; n < n1; n++) {
        int g = batch[n];
        if (g != cur) {
            atomicAdd(&out[cur * D + c], acc);
            acc = 0.f;
            cur = g;
        }
        acc += b2f(h[(size_t)n * D + c]);
    }
    atomicAdd(&out[cur * D + c], acc);
}

extern "C" void kernel_launch(void* const* d_in, const int* in_sizes, int n_in,
                              void* d_out, int out_size, void* d_ws, size_t ws_size,
                              hipStream_t stream) {
    const float* x = (const float*)d_in[0];
    const int* ei[4] = {(const int*)d_in[1], (const int*)d_in[2],
                        (const int*)d_in[3], (const int*)d_in[4]};
    const int* batch = (const int*)d_in[5];
    const float* emb_w = (const float*)d_in[6];
    const float* emb_b = (const float*)d_in[7];
    const float* root_w = (const float*)d_in[8];
    const float* root_b = (const float*)d_in[9];
    const float* conv_w = (const float*)d_in[10];
    float* out = (float*)d_out;

    const size_t WPT = (size_t)FIN * 128 + 20 * (size_t)128 * 128;  // permuted weights
    // choose G by ws capacity (ws_size constant across calls -> same path every launch)
    int G = 1;
    for (int g = 4; g >= 1; g >>= 1) {
        size_t need = ((size_t)NN * D * 2 + (size_t)g * (NN + 1) * D + (size_t)NN * FIN + WPT) * 2 +
                      ((size_t)NR * NN * (1 + CAPS)) * 4;
        if (ws_size >= need) { G = g; break; }
    }

    // workspace layout
    ushort* hb = (ushort*)d_ws;                          // NN*D
    ushort* ob = hb + (size_t)NN * D;                    // NN*D (base)
    ushort* mbuf = ob + (size_t)NN * D;                  // G*(NN+1)*D (key16, +dummy row)
    ushort* xb = mbuf + (size_t)G * (NN + 1) * D;        // NN*FIN
    ushort* wp = xb + (size_t)NN * FIN;                  // WPT
    int* deg = (int*)(wp + WPT);                         // NN*NR  (node-major)
    int* slots = deg + (size_t)NR * NN;                  // NN*NR*CAPS (src byte-offsets)
    ushort* wpEmb = wp;
    ushort* wpRoot = wp + (size_t)FIN * 128;
    ushort* wpConv = wpRoot + (size_t)4 * 128 * 128;

    // ---- adjacency build: zero deg + one-pass partitioned slot fill ----
    zero_i32<<<(NR * NN + 255) / 256, 256, 0, stream>>>(deg, NR * NN);
    {
        int nch = (NR * NE + EPB - 1) / EPB;
        slot_fill<<<nch * FP, 256, 0, stream>>>(ei[0], ei[1], ei[2], ei[3], deg, slots);
    }

    // ---- weight permute + input convert + dummy rows ----
    {
        int t1 = FIN * 128;
        wperm_kernel<<<(t1 + 255) / 256, 256, 0, stream>>>(emb_w, wpEmb, FIN, t1);
        int t2 = 4 * 128 * 128;
        wperm_kernel<<<(t2 + 255) / 256, 256, 0, stream>>>(root_w, wpRoot, 128, t2);
        int t3 = 16 * 128 * 128;
        wperm_kernel<<<(t3 + 255) / 256, 256, 0, stream>>>(conv_w, wpConv, 128, t3);
        int t4 = NN * FIN;
        xcvt<<<(t4 + 255) / 256, 256, 0, stream>>>(x, xb, t4);
        zero_dummy<<<(G * D + 255) / 256, 256, 0, stream>>>(mbuf, G);
    }

    // ---- embedding ----
    mgemm<FIN, 0><<<1024, 256, 0, stream>>>(xb, wpEmb, emb_b, hb);

    // ---- layers ----
    for (int l = 0; l < NL; l++) {
        if (G == 4) {
            mgemm5<<<dim3(640, 5), 256, 0, stream>>>(hb, wpRoot + (size_t)l * 128 * 128,
                                                     wpConv + (size_t)l * 4 * 128 * 128,
                                                     root_b + (size_t)l * D, ob, mbuf);
            agg_kernel<4><<<(NN + 3) / 4, 256, 0, stream>>>(mbuf, deg, slots, 0, ob, hb, 1);
        } else {
            mgemm<128, 0><<<1024, 256, 0, stream>>>(hb, wpRoot + (size_t)l * 128 * 128,
                                                    root_b + (size_t)l * D, ob);
            for (int g0 = 0; g0 < NR; g0 += G) {
                for (int r = g0; r < g0 + G; r++)
                    mgemm<128, 1><<<1024, 256, 0, stream>>>(
                        hb, wpConv + (size_t)(l * NR + r) * 128 * 128, nullptr,
                        mbuf + (size_t)(r - g0) * (NN + 1) * D);
                int last = (g0 + G == NR);
                if (G == 2)
                    agg_kernel<2><<<(NN + 3) / 4, 256, 0, stream>>>(
                        mbuf, deg, slots, g0, ob, last ? hb : ob, last ? 1 : 0);
                else
                    agg_kernel<1><<<(NN + 3) / 4, 256, 0, stream>>>(
                        mbuf, deg, slots, g0, ob, last ? hb : ob, last ? 1 : 0);
            }
        }
    }

    // ---- global add pool ----
    zero_f32<<<(NGR * D + 255) / 256, 256, 0, stream>>>(out, NGR * D);
    pool_kernel<<<(NN + PCH - 1) / PCH, 128, 0, stream>>>(hb, batch, out);
}

// Round 9
// 848.738 us; speedup vs baseline: 1.3241x; 1.0001x over previous
//
#include <hip/hip_runtime.h>

#define NN 100000   // nodes
#define NE 500000   // edges per relation
#define NR 4        // relations
#define NL 4        // layers
#define FIN 64      // input features
#define D 128       // embedding dim
#define NGR 64      // graphs

#define FP 8        // dst partitions (XCD round-robin heuristic)
#define PSZ ((NN + FP - 1) / FP)   // 12500 nodes per partition
#define EPB 4096    // edges per block chunk in slot_fill
#define CAPS 16     // slot capacity; dirty set/partition = 3.2MB < 4MB XCD L2
#define OVFCAP 8192 // overflow entries (expected ~10; P(deg>16|Poisson(5))~3e-5)

typedef __attribute__((ext_vector_type(8))) short short8;
typedef __attribute__((ext_vector_type(4))) float f32x4;
typedef __attribute__((ext_vector_type(2))) unsigned short u16x2;
typedef unsigned short ushort;
typedef unsigned int uint;

__device__ __forceinline__ ushort f2b(float f) {
    uint u = __float_as_uint(f);
    uint r = (u + 0x7fffu + ((u >> 16) & 1u)) >> 16;  // RNE
    return (ushort)r;
}
__device__ __forceinline__ float b2f(ushort b) {
    return __uint_as_float(((uint)b) << 16);
}
// monotone bf16 -> u16 key (order-isomorphic bijection); key 0 = -inf sentinel
__device__ __forceinline__ ushort enc16(ushort u) {
    return u ^ (ushort)((((short)u) >> 15) | (short)0x8000);
}
__device__ __forceinline__ ushort dec16(ushort k) {
    return k ^ (ushort)((((short)(k ^ 0x8000)) >> 15) | (short)0x8000);
}
__device__ __forceinline__ u16x2 vmax2(u16x2 a, u16x2 b) {
#if __has_builtin(__builtin_elementwise_max)
    return __builtin_elementwise_max(a, b);
#else
    u16x2 r;
    r.x = a.x > b.x ? a.x : b.x;
    r.y = a.y > b.y ? a.y : b.y;
    return r;
#endif
}

// ---------------- utility ----------------
__global__ void zero_i32(int* __restrict__ p, int n) {
    int i = blockIdx.x * blockDim.x + threadIdx.x;
    if (i < n) p[i] = 0;
}
__global__ void zero_f32(float* __restrict__ p, int n) {
    int i = blockIdx.x * blockDim.x + threadIdx.x;
    if (i < n) p[i] = 0.f;
}
__global__ void xcvt(const float* __restrict__ x, ushort* __restrict__ xb, int n) {
    int i = blockIdx.x * blockDim.x + threadIdx.x;
    if (i < n) xb[i] = f2b(x[i]);
}
// zero the dummy row (index NN) of each of the G m-buffers (stride (NN+1)*D)
__global__ void zero_dummy(ushort* __restrict__ mbuf, int G) {
    int i = blockIdx.x * blockDim.x + threadIdx.x;
    if (i < G * D)
        mbuf[(size_t)(i / D) * (NN + 1) * D + (size_t)NN * D + (i % D)] = 0;
}

// W fp32 [nmat][K x 128] -> bf16 MFMA B-fragment order
__global__ void wperm_kernel(const float* __restrict__ W, ushort* __restrict__ dst,
                             int K, int total) {
    int i = blockIdx.x * blockDim.x + threadIdx.x;
    if (i >= total) return;
    int per = K * 128;
    int mi = i / per;
    int o = i - mi * per;
    int j = o & 7, lane = (o >> 3) & 63, rest = o >> 9;
    int K032 = K / 32;
    int k0 = rest % K032, t = rest / K032;
    int k = k0 * 32 + (lane >> 4) * 8 + j;
    int n = t * 16 + (lane & 15);
    dst[i] = f2b(W[(size_t)mi * per + k * 128 + n]);
}

// ---------------- one-pass slotted adjacency build, XCD-partitioned ----------------
// deg[node*NR + r]; slots[(node*NR + r)*CAPS + slot] = src byte-offset.
// Slots beyond CAPS spill to a tiny global overflow list (expected ~10 entries).
__global__ __launch_bounds__(256) void slot_fill(const int* __restrict__ e0,
                                                 const int* __restrict__ e1,
                                                 const int* __restrict__ e2,
                                                 const int* __restrict__ e3,
                                                 int* __restrict__ deg,
                                                 int* __restrict__ slots,
                                                 int* __restrict__ ovf_cnt,
                                                 int* __restrict__ ovf) {
    const int part = blockIdx.x % FP;
    const int chunk = blockIdx.x / FP;
    const int plo = part * PSZ;
    const int phi = (plo + PSZ < NN) ? plo + PSZ : NN;
    const int i0 = chunk * EPB;
    int i1 = i0 + EPB; if (i1 > NR * NE) i1 = NR * NE;
    for (int i = i0 + threadIdx.x; i < i1; i += 256) {
        int r = i / NE, j = i - r * NE;
        const int* ei = (r == 0) ? e0 : (r == 1) ? e1 : (r == 2) ? e2 : e3;
        int d = __builtin_nontemporal_load(&ei[NE + j]);
        if (d >= plo && d < phi) {
            int s = __builtin_nontemporal_load(&ei[j]);
            int slot = atomicAdd(&deg[d * NR + r], 1);
            if (slot < CAPS) {
                slots[((size_t)d * NR + r) * CAPS + slot] = s * (D * 2);
            } else {
                int oi = atomicAdd(ovf_cnt, 1);
                if (oi < OVFCAP) {
                    ovf[2 * oi] = d * NR + r;
                    ovf[2 * oi + 1] = s * (D * 2);
                }
            }
        }
    }
}

// ---------------- bf16 MFMA GEMM (embedding / fallback) ----------------
template <int K, int MODE>
__global__ __launch_bounds__(256) void mgemm(const ushort* __restrict__ A,
                                             const ushort* __restrict__ Bp,
                                             const float* __restrict__ bias,
                                             ushort* __restrict__ Ch) {
    constexpr int K032 = K / 32;
    __shared__ ushort Bs[8 * K032 * 64 * 8];
    const int tid = threadIdx.x;
    for (int i = tid; i < K * 16; i += 256)
        ((float4*)Bs)[i] = ((const float4*)Bp)[i];
    const int lane = tid & 63, wave = tid >> 6;
    const int quad = lane >> 4, l15 = lane & 15;
    const int ch = wave & 1, rg = wave >> 1;
    __syncthreads();
    short8 breg[4][K032];
#pragma unroll
    for (int tt = 0; tt < 4; tt++)
#pragma unroll
        for (int k0 = 0; k0 < K032; k0++)
            breg[tt][k0] = *(const short8*)&Bs[(size_t)(((ch * 4 + tt) * K032 + k0) * 64 + lane) * 8];
    float bv[4] = {0.f, 0.f, 0.f, 0.f};
    if (bias)
#pragma unroll
        for (int tt = 0; tt < 4; tt++) bv[tt] = bias[(ch * 4 + tt) * 16 + l15];
    for (int tile = blockIdx.x; tile < NN / 32; tile += gridDim.x) {
        const int row0 = tile * 32 + rg * 16;
        const ushort* Ar = A + (size_t)(row0 + l15) * K + quad * 8;
        short8 a[K032];
#pragma unroll
        for (int k0 = 0; k0 < K032; k0++) a[k0] = *(const short8*)(Ar + k0 * 32);
        f32x4 acc[4];
#pragma unroll
        for (int tt = 0; tt < 4; tt++) acc[tt] = (f32x4){bv[tt], bv[tt], bv[tt], bv[tt]};
#pragma unroll
        for (int k0 = 0; k0 < K032; k0++)
#pragma unroll
            for (int tt = 0; tt < 4; tt++)
                acc[tt] = __builtin_amdgcn_mfma_f32_16x16x32_bf16(a[k0], breg[tt][k0], acc[tt], 0, 0, 0);
#pragma unroll
        for (int tt = 0; tt < 4; tt++) {
            const int col = (ch * 4 + tt) * 16 + l15;
#pragma unroll
            for (int r = 0; r < 4; r++) {
                ushort v = f2b(acc[tt][r]);
                if (MODE == 1) v = enc16(v);
                Ch[(size_t)(row0 + quad * 4 + r) * D + col] = v;
            }
        }
    }
}

// ---------------- fused per-layer GEMM: blockIdx.y = matrix (0=root, 1..4=conv r) ----------------
__global__ __launch_bounds__(256) void mgemm5(const ushort* __restrict__ A,
                                              const ushort* __restrict__ wpRootL,
                                              const ushort* __restrict__ wpConvL,
                                              const float* __restrict__ biasL,
                                              ushort* __restrict__ ob,
                                              ushort* __restrict__ mbuf) {
    constexpr int K032 = 4;  // K=128
    const int m = blockIdx.y;
    const ushort* Bp = (m == 0) ? wpRootL : wpConvL + (size_t)(m - 1) * 128 * 128;
    ushort* Ch = (m == 0) ? ob : mbuf + (size_t)(m - 1) * (NN + 1) * D;
    const bool key = (m != 0);
    __shared__ ushort Bs[8 * K032 * 64 * 8];
    const int tid = threadIdx.x;
    for (int i = tid; i < 128 * 16; i += 256)
        ((float4*)Bs)[i] = ((const float4*)Bp)[i];
    const int lane = tid & 63, wave = tid >> 6;
    const int quad = lane >> 4, l15 = lane & 15;
    const int ch = wave & 1, rg = wave >> 1;
    __syncthreads();
    short8 breg[4][K032];
#pragma unroll
    for (int tt = 0; tt < 4; tt++)
#pragma unroll
        for (int k0 = 0; k0 < K032; k0++)
            breg[tt][k0] = *(const short8*)&Bs[(size_t)(((ch * 4 + tt) * K032 + k0) * 64 + lane) * 8];
    float bv[4] = {0.f, 0.f, 0.f, 0.f};
    if (m == 0)
#pragma unroll
        for (int tt = 0; tt < 4; tt++) bv[tt] = biasL[(ch * 4 + tt) * 16 + l15];
    for (int tile = blockIdx.x; tile < NN / 32; tile += gridDim.x) {
        const int row0 = tile * 32 + rg * 16;
        const ushort* Ar = A + (size_t)(row0 + l15) * 128 + quad * 8;
        short8 a[K032];
#pragma unroll
        for (int k0 = 0; k0 < K032; k0++) a[k0] = *(const short8*)(Ar + k0 * 32);
        f32x4 acc[4];
#pragma unroll
        for (int tt = 0; tt < 4; tt++) acc[tt] = (f32x4){bv[tt], bv[tt], bv[tt], bv[tt]};
#pragma unroll
        for (int k0 = 0; k0 < K032; k0++)
#pragma unroll
            for (int tt = 0; tt < 4; tt++)
                acc[tt] = __builtin_amdgcn_mfma_f32_16x16x32_bf16(a[k0], breg[tt][k0], acc[tt], 0, 0, 0);
#pragma unroll
        for (int tt = 0; tt < 4; tt++) {
            const int col = (ch * 4 + tt) * 16 + l15;
#pragma unroll
            for (int r = 0; r < 4; r++) {
                ushort v = f2b(acc[tt][r]);
                if (key) v = enc16(v);
                Ch[(size_t)(row0 + quad * 4 + r) * D + col] = v;
            }
        }
    }
}

// ---------------- interleaved multi-relation scatter-max, 4-wide unrolled ----------------
// mb: G buffers of (NN+1)*D key16; row NN of each = zeroed dummy (-inf keys).
// Invalid (g,i) gathers are redirected to the dummy row -> branchless, max-neutral.
// Overflow entries (deg > CAPS) are scanned per wave (expected ~10 total, L2-hot).
template <int G>
__global__ __launch_bounds__(256) void agg_kernel(const ushort* __restrict__ mb,
                                                  const int* __restrict__ deg,
                                                  const int* __restrict__ slots,
                                                  const int* __restrict__ ovf_cnt,
                                                  const int* __restrict__ ovf,
                                                  int g0,
                                                  const ushort* __restrict__ base,
                                                  ushort* __restrict__ outh,
                                                  int do_relu) {
    const int wv = threadIdx.x >> 6;
    const int lane = threadIdx.x & 63;
    const int node = blockIdx.x * 4 + wv;
    if (node >= NN) return;
    const int DUM = NN * D * 2;  // byte offset of dummy row
    const int* db = deg + (size_t)node * NR + g0;
    const int* sb = slots + ((size_t)node * NR + g0) * CAPS;
    int nd[G], s_l[G];
    const char* ml[G];
#pragma unroll
    for (int g = 0; g < G; g++) {
        int n = db[g];
        nd[g] = (n > CAPS) ? CAPS : n;
        s_l[g] = (lane < nd[g]) ? sb[g * CAPS + lane] : DUM;
        ml[g] = (const char*)(mb + (size_t)g * (NN + 1) * D) + lane * 4;
    }
    int ndmax = 0;
#pragma unroll
    for (int g = 0; g < G; g++) ndmax = (nd[g] > ndmax) ? nd[g] : ndmax;
    u16x2 acc[G];
#pragma unroll
    for (int g = 0; g < G; g++) acc[g] = (u16x2)0;
    for (int i = 0; i < ndmax; i += 4) {
        int s[G][4];
#pragma unroll
        for (int g = 0; g < G; g++) {
#pragma unroll
            for (int u = 0; u < 4; u++) {
                int sv = __shfl(s_l[g], i + u);
                s[g][u] = (i + u < nd[g]) ? sv : DUM;
            }
        }
#pragma unroll
        for (int g = 0; g < G; g++) {
            u16x2 v0 = *(const u16x2*)(ml[g] + s[g][0]);
            u16x2 v1 = *(const u16x2*)(ml[g] + s[g][1]);
            u16x2 v2 = *(const u16x2*)(ml[g] + s[g][2]);
            u16x2 v3 = *(const u16x2*)(ml[g] + s[g][3]);
            acc[g] = vmax2(acc[g], vmax2(vmax2(v0, v1), vmax2(v2, v3)));
        }
    }
    // rare overflow edges (deg > CAPS): wave-uniform scan of tiny list
    int novf = *ovf_cnt;
    if (novf > OVFCAP) novf = OVFCAP;
    for (int i = 0; i < novf; i++) {
        int edr = ovf[2 * i];
        int dr = edr - (node * NR + g0);
        if (dr >= 0 && dr < G) {
            int so = ovf[2 * i + 1];
#pragma unroll
            for (int g = 0; g < G; g++)
                if (dr == g)
                    acc[g] = vmax2(acc[g], *(const u16x2*)(ml[g] + so));
        }
    }
    uint bp = ((const uint*)(base + (size_t)node * D))[lane];
    float rx = __uint_as_float(bp << 16), ry = __uint_as_float(bp & 0xffff0000u);
#pragma unroll
    for (int g = 0; g < G; g++) {
        rx += (nd[g] > 0) ? b2f(dec16(acc[g].x)) : 0.f;
        ry += (nd[g] > 0) ? b2f(dec16(acc[g].y)) : 0.f;
    }
    if (do_relu) { rx = fmaxf(rx, 0.f); ry = fmaxf(ry, 0.f); }
    uint pk = (uint)f2b(rx) | ((uint)f2b(ry) << 16);
    ((uint*)(outh + (size_t)node * D))[lane] = pk;
}

// ---------------- global add pool (batch sorted), h in bf16 ----------------
#define PCH 256
__global__ __launch_bounds__(128) void pool_kernel(const ushort* __restrict__ h,
                                                   const int* __restrict__ batch,
                                                   float* __restrict__ out) {
    int c = threadIdx.x;
    int n0 = blockIdx.x * PCH;
    if (n0 >= NN) return;
    int n1 = n0 + PCH; if (n1 > NN) n1 = NN;
    int cur = batch[n0];
    float acc = 0.f;
    for (int n = n0; n < n1; n++) {
        int g = batch[n];
        if (g != cur) {
            atomicAdd(&out[cur * D + c], acc);
            acc = 0.f;
            cur = g;
        }
        acc += b2f(h[(size_t)n * D + c]);
    }
    atomicAdd(&out[cur * D + c], acc);
}

extern "C" void kernel_launch(void* const* d_in, const int* in_sizes, int n_in,
                              void* d_out, int out_size, void* d_ws, size_t ws_size,
                              hipStream_t stream) {
    const float* x = (const float*)d_in[0];
    const int* ei[4] = {(const int*)d_in[1], (const int*)d_in[2],
                        (const int*)d_in[3], (const int*)d_in[4]};
    const int* batch = (const int*)d_in[5];
    const float* emb_w = (const float*)d_in[6];
    const float* emb_b = (const float*)d_in[7];
    const float* root_w = (const float*)d_in[8];
    const float* root_b = (const float*)d_in[9];
    const float* conv_w = (const float*)d_in[10];
    float* out = (float*)d_out;

    const size_t WPT = (size_t)FIN * 128 + 20 * (size_t)128 * 128;  // permuted weights
    const size_t intWords = (size_t)NR * NN * (1 + CAPS) + 1 + 2 * OVFCAP;
    // choose G by ws capacity (ws_size constant across calls -> same path every launch)
    int G = 1;
    for (int g = 4; g >= 1; g >>= 1) {
        size_t need = ((size_t)NN * D * 2 + (size_t)g * (NN + 1) * D + (size_t)NN * FIN + WPT) * 2 +
                      intWords * 4;
        if (ws_size >= need) { G = g; break; }
    }

    // workspace layout
    ushort* hb = (ushort*)d_ws;                          // NN*D
    ushort* ob = hb + (size_t)NN * D;                    // NN*D (base)
    ushort* mbuf = ob + (size_t)NN * D;                  // G*(NN+1)*D (key16, +dummy row)
    ushort* xb = mbuf + (size_t)G * (NN + 1) * D;        // NN*FIN
    ushort* wp = xb + (size_t)NN * FIN;                  // WPT
    int* deg = (int*)(wp + WPT);                         // NN*NR  (node-major)
    int* ovf_cnt = deg + (size_t)NR * NN;                // 1
    int* slots = ovf_cnt + 1;                            // NN*NR*CAPS (src byte-offsets)
    int* ovf = slots + (size_t)NR * NN * CAPS;           // 2*OVFCAP
    ushort* wpEmb = wp;
    ushort* wpRoot = wp + (size_t)FIN * 128;
    ushort* wpConv = wpRoot + (size_t)4 * 128 * 128;

    // ---- adjacency build: zero deg+ovf_cnt + one-pass partitioned slot fill ----
    zero_i32<<<(NR * NN + 1 + 255) / 256, 256, 0, stream>>>(deg, NR * NN + 1);
    {
        int nch = (NR * NE + EPB - 1) / EPB;
        slot_fill<<<nch * FP, 256, 0, stream>>>(ei[0], ei[1], ei[2], ei[3],
                                                deg, slots, ovf_cnt, ovf);
    }

    // ---- weight permute + input convert + dummy rows ----
    {
        int t1 = FIN * 128;
        wperm_kernel<<<(t1 + 255) / 256, 256, 0, stream>>>(emb_w, wpEmb, FIN, t1);
        int t2 = 4 * 128 * 128;
        wperm_kernel<<<(t2 + 255) / 256, 256, 0, stream>>>(root_w, wpRoot, 128, t2);
        int t3 = 16 * 128 * 128;
        wperm_kernel<<<(t3 + 255) / 256, 256, 0, stream>>>(conv_w, wpConv, 128, t3);
        int t4 = NN * FIN;
        xcvt<<<(t4 + 255) / 256, 256, 0, stream>>>(x, xb, t4);
        zero_dummy<<<(G * D + 255) / 256, 256, 0, stream>>>(mbuf, G);
    }

    // ---- embedding ----
    mgemm<FIN, 0><<<1024, 256, 0, stream>>>(xb, wpEmb, emb_b, hb);

    // ---- layers ----
    for (int l = 0; l < NL; l++) {
        if (G == 4) {
            mgemm5<<<dim3(640, 5), 256, 0, stream>>>(hb, wpRoot + (size_t)l * 128 * 128,
                                                     wpConv + (size_t)l * 4 * 128 * 128,
                                                     root_b + (size_t)l * D, ob, mbuf);
            agg_kernel<4><<<(NN + 3) / 4, 256, 0, stream>>>(mbuf, deg, slots, ovf_cnt, ovf,
                                                            0, ob, hb, 1);
        } else {
            mgemm<128, 0><<<1024, 256, 0, stream>>>(hb, wpRoot + (size_t)l * 128 * 128,
                                                    root_b + (size_t)l * D, ob);
            for (int g0 = 0; g0 < NR; g0 += G) {
                for (int r = g0; r < g0 + G; r++)
                    mgemm<128, 1><<<1024, 256, 0, stream>>>(
                        hb, wpConv + (size_t)(l * NR + r) * 128 * 128, nullptr,
                        mbuf + (size_t)(r - g0) * (NN + 1) * D);
                int last = (g0 + G == NR);
                if (G == 2)
                    agg_kernel<2><<<(NN + 3) / 4, 256, 0, stream>>>(
                        mbuf, deg, slots, ovf_cnt, ovf, g0, ob, last ? hb : ob, last ? 1 : 0);
                else
                    agg_kernel<1><<<(NN + 3) / 4, 256, 0, stream>>>(
                        mbuf, deg, slots, ovf_cnt, ovf, g0, ob, last ? hb : ob, last ? 1 : 0);
            }
        }
    }

    // ---- global add pool ----
    zero_f32<<<(NGR * D + 255) / 256, 256, 0, stream>>>(out, NGR * D);
    pool_kernel<<<(NN + PCH - 1) / PCH, 128, 0, stream>>>(hb, batch, out);
}